// Round 9
// baseline (506.195 us; speedup 1.0000x reference)
//
#include <hip/hip_runtime.h>
#include <hip/hip_bf16.h>
#include <type_traits>

#define DIN   7686
#define NNODE 7946
#define HOUT  260
#define KP    8192   // padded k (64 kc-blocks of 128)
#define PLDS  2056   // panel row stride in shorts (2048 + 8 pad)

typedef __attribute__((ext_vector_type(8))) short bf16x8;
typedef __attribute__((ext_vector_type(4))) float f32x4;

__device__ __forceinline__ unsigned int f2b(float f) {
  union { float f; unsigned int u; } v; v.f = f;
  return (v.u + 0x7FFFu + ((v.u >> 16) & 1u)) >> 16;  // RNE float->bf16
}
__device__ __forceinline__ unsigned int pack2(float lo, float hi) {
  unsigned int r;
  asm("v_cvt_pk_bf16_f32 %0, %1, %2" : "=v"(r) : "v"(lo), "v"(hi));
  return r;
}
__device__ __forceinline__ float b2f(unsigned short h) {
  union { unsigned int u; float f; } v; v.u = ((unsigned int)h) << 16; return v.f;
}
__device__ __forceinline__ float readlane_f(float v, int lane) {
  return __uint_as_float(__builtin_amdgcn_readlane(__float_as_uint(v), lane));
}

// ---------------------------------------------------------------------------
// prep_x2 (R7, verified): fp32 X -> bf16 FRAGMENT-MAJOR for direct MFMA A-loads
// block(kc 0..63, i16 0..15, ks 0..3) = 1KB at ((kc*16+i16)*4+ks)*1024.
// lane l: m = i16*16 + (l&15), k = kc*128 + ks*32 + (l>>4)*8 .. +8. Pads zero.
// ---------------------------------------------------------------------------
__global__ void prep_x2(const float* __restrict__ X, char* __restrict__ XbT2)
{
  const int m = blockIdx.x, t = threadIdx.x;
  const float* row = X + (size_t)m * DIN;
  const int i16 = m >> 4;
#pragma unroll
  for (int c2 = 0; c2 < 4; ++c2) {
    const int k8 = (c2 * 256 + t) * 8;
    float f[8];
    if (k8 + 8 <= DIN) {
#pragma unroll
      for (int h = 0; h < 4; ++h) {
        float2 v = *(const float2*)(row + k8 + h * 2);
        f[h * 2] = v.x; f[h * 2 + 1] = v.y;
      }
    } else {
#pragma unroll
      for (int h = 0; h < 8; ++h) f[h] = (k8 + h < DIN) ? row[k8 + h] : 0.f;
    }
    uint4 o;
    o.x = pack2(f[0], f[1]); o.y = pack2(f[2], f[3]);
    o.z = pack2(f[4], f[5]); o.w = pack2(f[6], f[7]);
    const int kc = k8 >> 7, kk = k8 & 127, ks = kk >> 5, hq = (kk & 31) >> 3;
    const int lane = (m & 15) + (hq << 4);
    char* dst = XbT2 + ((((size_t)kc * 16 + i16) * 4 + ks) << 10) + lane * 16;
    *(uint4*)dst = o;
  }
}

// ---------------------------------------------------------------------------
// gemm_qk5: panel GEMM. WG = 32 W-rows x K-quarter(2048). 512 thr = 8 waves.
// Phase 1: each wave streams 4 rows SEQUENTIALLY (page-dense, lane-contig
//   float2 pairs) -> bf16 LDS panel [32][PLDS] (128.5 KB). ONE barrier.
// Phase 2: no barriers. B-frags from LDS; A-frags direct global from
//   fragment-major XbT2 (L2-resident). acc 2x2 16x16 tiles per wave.
// Out: bf16 partial per (mat, quarter) -> PQK[(mat*4+z)][256][KP].
// grid (241, 2, 4) = 1928 WGs. 1 WG/CU (LDS-bound).
// ---------------------------------------------------------------------------
__global__ __launch_bounds__(512, 1)
void gemm_qk5(const char* __restrict__ XbT2,
              const float* __restrict__ Wq, const float* __restrict__ Wk,
              unsigned short* __restrict__ PQK)
{
  const int mat = blockIdx.y, z = blockIdx.z;
  const float* W = mat ? Wk : Wq;
  const int n0 = blockIdx.x * 32;
  const int tid = threadIdx.x, l = tid & 63, wv = tid >> 6;
  const int lm = l & 15, hq = l >> 4;

  __shared__ __align__(16) unsigned short Bp[32 * PLDS];  // 131,584 B

  const long long DD = (long long)DIN * DIN;
  const int kq0 = z * 2048;

  // ---- phase 1: panel load, row-sequential per wave ----
#pragma unroll
  for (int r = 0; r < 4; ++r) {
    const int lrow = wv * 4 + r;
    int grow = n0 + lrow; if (grow > DIN - 1) grow = DIN - 1;
    const long long gbase = (long long)grow * DIN + kq0;
    unsigned short* dst = &Bp[lrow * PLDS];
#pragma unroll
    for (int c = 0; c < 8; ++c) {
      const int k = c * 256 + l * 4;
      long long g0 = gbase + k, g1 = gbase + k + 2;
      if (g0 + 2 > DD) g0 = DD - 2;     // tail-safe; values don't-care (A=0)
      if (g1 + 2 > DD) g1 = DD - 2;
      float2 v0 = *(const float2*)(W + g0);
      float2 v1 = *(const float2*)(W + g1);
      uint2 o; o.x = pack2(v0.x, v0.y); o.y = pack2(v1.x, v1.y);
      *(uint2*)(dst + k) = o;
    }
  }
  __syncthreads();   // the ONLY barrier

  // ---- phase 2: compute (wave wv owns m-band wv*32..wv*32+31) ----
  f32x4 acc[2][2] = {};   // [i (m 16-blk)][nb (n 16-blk)]
  const int kcB = z * 16;
#pragma unroll 4
  for (int ks = 0; ks < 64; ++ks) {
    const int kc = kcB + (ks >> 2), kss = ks & 3;
    bf16x8 b0 = *(const bf16x8*)&Bp[lm * PLDS + ks * 32 + hq * 8];
    bf16x8 b1 = *(const bf16x8*)&Bp[(16 + lm) * PLDS + ks * 32 + hq * 8];
    const char* abase = XbT2 + ((((size_t)kc * 16 + 2 * wv) * 4 + kss) << 10) + l * 16;
    bf16x8 a0 = *(const bf16x8*)abase;
    bf16x8 a1 = *(const bf16x8*)(abase + 4096);
    acc[0][0] = __builtin_amdgcn_mfma_f32_16x16x32_bf16(a0, b0, acc[0][0], 0, 0, 0);
    acc[0][1] = __builtin_amdgcn_mfma_f32_16x16x32_bf16(a0, b1, acc[0][1], 0, 0, 0);
    acc[1][0] = __builtin_amdgcn_mfma_f32_16x16x32_bf16(a1, b0, acc[1][0], 0, 0, 0);
    acc[1][1] = __builtin_amdgcn_mfma_f32_16x16x32_bf16(a1, b1, acc[1][1], 0, 0, 0);
  }

  // ---- epilogue: bf16 partial store ----
  unsigned short* Cp = PQK + ((size_t)(mat * 4 + z) * 256) * KP;
#pragma unroll
  for (int i = 0; i < 2; ++i) {
    const int r0 = wv * 32 + i * 16 + hq * 4;
#pragma unroll
    for (int nb = 0; nb < 2; ++nb) {
      const int col = n0 + nb * 16 + lm;
#pragma unroll
      for (int q = 0; q < 4; ++q)
        Cp[(size_t)(r0 + q) * KP + col] = (unsigned short)f2b(acc[i][nb][q]);
    }
  }
}

// ---------------------------------------------------------------------------
// reduce_qk4: sum 4 bf16 partials + bias -> Qbf/Kbf bf16 [256][KP], pads zero
// grid (64, 2) x 128 threads
// ---------------------------------------------------------------------------
__global__ void reduce_qk4(const unsigned short* __restrict__ PQK,
                           const float* __restrict__ bq, const float* __restrict__ bk,
                           unsigned short* __restrict__ Qbf, unsigned short* __restrict__ Kbf)
{
  const int mat = blockIdx.y;
  const int c = blockIdx.x * 128 + threadIdx.x;
  const float* bias = mat ? bk : bq;
  const bool valid = c < DIN;
  const float bb = valid ? bias[c] : 0.f;
  const unsigned short* P0 = PQK + ((size_t)(mat * 4 + 0) * 256) * KP + c;
  const unsigned short* P1 = PQK + ((size_t)(mat * 4 + 1) * 256) * KP + c;
  const unsigned short* P2 = PQK + ((size_t)(mat * 4 + 2) * 256) * KP + c;
  const unsigned short* P3 = PQK + ((size_t)(mat * 4 + 3) * 256) * KP + c;
  unsigned short* O = (mat ? Kbf : Qbf) + c;
#pragma unroll 4
  for (int r = 0; r < 256; ++r) {
    float v = b2f(P0[(size_t)r * KP]) + b2f(P1[(size_t)r * KP]) +
              b2f(P2[(size_t)r * KP]) + b2f(P3[(size_t)r * KP]) + bb;
    if (!valid) v = 0.f;
    O[(size_t)r * KP] = (unsigned short)f2b(v);
  }
}

// ---------------------------------------------------------------------------
// logits partials: LP[z][m][n] = sum_{k in 512-chunk z} Q[m,k]*K[n,k]
// grid (4, 1, 16) x 512.
// ---------------------------------------------------------------------------
__global__ __launch_bounds__(512)
void gemm_logits(const unsigned short* __restrict__ Qbf,
                 const unsigned short* __restrict__ Kbf, float* __restrict__ LP)
{
  const int qr = blockIdx.x & 1, qc = blockIdx.x >> 1, z = blockIdx.z;
  const int tid = threadIdx.x, lane = tid & 63, wv = tid >> 6;
  const int lm = lane & 15, lq = (lane >> 4) * 8;
  const int rowBase = qr * 128 + (wv & 3) * 32;
  const int colBase = qc * 128 + (wv >> 2) * 64;
  const int k0 = z * 512;
  f32x4 acc[2][4] = {};
#pragma unroll 4
  for (int ks = 0; ks < 16; ++ks) {
    bf16x8 a[2], b[4];
#pragma unroll
    for (int i = 0; i < 2; ++i)
      a[i] = *(const bf16x8*)(Qbf + (size_t)(rowBase + i * 16 + lm) * KP + k0 + ks * 32 + lq);
#pragma unroll
    for (int j = 0; j < 4; ++j)
      b[j] = *(const bf16x8*)(Kbf + (size_t)(colBase + j * 16 + lm) * KP + k0 + ks * 32 + lq);
#pragma unroll
    for (int i = 0; i < 2; ++i)
#pragma unroll
      for (int j = 0; j < 4; ++j)
        acc[i][j] = __builtin_amdgcn_mfma_f32_16x16x32_bf16(a[i], b[j], acc[i][j], 0, 0, 0);
  }
  float* out = LP + (size_t)z * 65536;
#pragma unroll
  for (int i = 0; i < 2; ++i) {
    const int r0 = rowBase + i * 16 + (lane >> 4) * 4;
#pragma unroll
    for (int j = 0; j < 4; ++j) {
      const int col = colBase + j * 16 + lm;
#pragma unroll
      for (int q = 0; q < 4; ++q)
        out[(size_t)(r0 + q) * 256 + col] = acc[i][j][q];
    }
  }
}

// ---------------------------------------------------------------------------
// fused: sum 16 logit partials -> row softmax -> atomicAdd into abar (w/ 1/256)
// ---------------------------------------------------------------------------
__global__ void softmax_fused(const float* __restrict__ LP, float* __restrict__ abar)
{
  __shared__ float red[8];
  const int m = blockIdx.x, t = threadIdx.x;
  float v = 0.f;
#pragma unroll
  for (int zz = 0; zz < 16; ++zz) v += LP[(size_t)zz * 65536 + m * 256 + t];
  const float scale = 1.0f / sqrtf((float)DIN);
  float mx = v;
#pragma unroll
  for (int o = 32; o >= 1; o >>= 1) mx = fmaxf(mx, __shfl_xor(mx, o, 64));
  if ((t & 63) == 0) red[t >> 6] = mx;
  __syncthreads();
  mx = fmaxf(fmaxf(red[0], red[1]), fmaxf(red[2], red[3]));
  float e = __expf((v - mx) * scale);
  float s = e;
#pragma unroll
  for (int o = 32; o >= 1; o >>= 1) s += __shfl_xor(s, o, 64);
  if ((t & 63) == 0) red[4 + (t >> 6)] = s;
  __syncthreads();
  s = red[4] + red[5] + red[6] + red[7];
  atomicAdd(&abar[t], e * (1.0f / 256.0f) / s);
}

// y[c] = sum_m abar[m] * X[m][c]
__global__ void y_kernel(const float* __restrict__ X, const float* __restrict__ abar,
                         float* __restrict__ y)
{
  __shared__ float ab[256];
  ab[threadIdx.x] = abar[threadIdx.x];
  __syncthreads();
  const int c = blockIdx.x * 256 + threadIdx.x;
  if (c >= DIN) return;
  float s = 0.f;
#pragma unroll 8
  for (int m = 0; m < 256; ++m) s += ab[m] * X[(size_t)m * DIN + c];
  y[c] = s;
}

// ctx[d] = Wv[d,:]·y + bv[d] — one row per wave, lane-contiguous stream
__global__ __launch_bounds__(512)
void ctx_mv(const float* __restrict__ Wv, const float* __restrict__ y,
            const float* __restrict__ bv, float* __restrict__ ctx)
{
  const int wv = threadIdx.x >> 6, l = threadIdx.x & 63;
  const int row = blockIdx.x * 8 + wv;
  if (row >= DIN) return;
  const float* wr_ = Wv + (size_t)row * DIN;
  float s = 0.f;
#pragma unroll 4
  for (int it = 0; it < 61; ++it) {
    const int k = it * 128 + l * 2;
    if (k < DIN) {
      float2 w2 = *(const float2*)(wr_ + k);
      float2 y2 = *(const float2*)(y + k);
      s = fmaf(w2.x, y2.x, s);
      s = fmaf(w2.y, y2.y, s);
    }
  }
#pragma unroll
  for (int o = 32; o >= 1; o >>= 1) s += __shfl_xor(s, o, 64);
  if (l == 0) ctx[row] = s + bv[row];
}

// base[j] += sum_{i in chunk} ctx[i] * (mu+sg*ep)[i][DIN+j]
__global__ void base_kernel(const float* __restrict__ mu, const float* __restrict__ sg,
                            const float* __restrict__ ep, const float* __restrict__ ctx,
                            float* __restrict__ base)
{
  const int j = threadIdx.x;
  if (j >= HOUT) return;
  const int i0 = blockIdx.x * 31;
  const int i1 = min(i0 + 31, DIN);
  float acc = 0.f;
#pragma unroll 4
  for (int i = i0; i < i1; ++i) {
    const size_t idx = (size_t)i * NNODE + DIN + j;
    acc = fmaf(ctx[i], fmaf(sg[idx], ep[idx], mu[idx]), acc);
  }
  atomicAdd(&base[j], acc);
}

// WsG[t][j] = (mu+sg*ep)[DIN+t][DIN+j]
__global__ void ws_kernel(const float* __restrict__ mu, const float* __restrict__ sg,
                          const float* __restrict__ ep, float* __restrict__ WsG)
{
  const int t = blockIdx.x;
  const int j = threadIdx.x;
  if (j >= HOUT) return;
  const size_t idx = (size_t)(DIN + t) * NNODE + DIN + j;
  WsG[t * HOUT + j] = fmaf(sg[idx], ep[idx], mu[idx]);
}

// ---------------------------------------------------------------------------
// scan2: latency-minimal sequential NEAT scan. 1 wave.
// ---------------------------------------------------------------------------
__global__ __launch_bounds__(64, 1)
void scan2(const float* __restrict__ WsG, const float* __restrict__ base,
           const float* __restrict__ bmu, const float* __restrict__ bsg,
           const float* __restrict__ epb, float* __restrict__ out)
{
  __shared__ __align__(16) float tile[32 * HOUT + 128];
  const int l = threadIdx.x;

  float a0, a1, a2, a3, a4;
  {
    int j = l;       a0 = base[j] + bmu[j] + bsg[j] * epb[j];
    j = l + 64;      a1 = base[j] + bmu[j] + bsg[j] * epb[j];
    j = l + 128;     a2 = base[j] + bmu[j] + bsg[j] * epb[j];
    j = l + 192;     a3 = base[j] + bmu[j] + bsg[j] * epb[j];
    j = l + 256;     a4 = (j < HOUT) ? (base[j] + bmu[j] + bsg[j] * epb[j]) : 0.f;
  }

  float4 stg[33];
  auto LOADT = [&](int tb) {
    const int nfl = ((tb == 8) ? 4 : 32) * HOUT;
    const float* src = WsG + tb * 32 * HOUT;
#pragma unroll
    for (int c = 0; c < 33; ++c) {
      const int o = c * 256 + l * 4;
      if (o < nfl) stg[c] = *(const float4*)(src + o);
    }
  };
  auto WRITET = [&](int tb) {
    const int nfl = ((tb == 8) ? 4 : 32) * HOUT;
#pragma unroll
    for (int c = 0; c < 33; ++c) {
      const int o = c * 256 + l * 4;
      if (o < nfl) *(float4*)&tile[o] = stg[c];
    }
  };

  float w0, w1, w2, w3, w4;
  auto PRER = [&](int trow) {
    const float* tr = tile + trow * HOUT;
    w0 = tr[l]; w1 = tr[l + 64]; w2 = tr[l + 128]; w3 = tr[l + 192]; w4 = tr[l + 256];
  };

  auto inner = [&](auto Bc, int tb, int nrows) {
    constexpr int B = Bc.value;
    for (int tt = 0; tt < nrows; ++tt) {
      const int t = tb * 32 + tt;
      float pre;
      if constexpr (B == 0) pre = readlane_f(a0, t & 63);
      else if constexpr (B == 1) pre = readlane_f(a1, t & 63);
      else if constexpr (B == 2) pre = readlane_f(a2, t & 63);
      else if constexpr (B == 3) pre = readlane_f(a3, t & 63);
      else pre = readlane_f(a4, t & 63);
      const float pc = fminf(fmaxf(pre, -12.f), 12.f);
      const float e = __expf(2.f * pc);
      const float vt = 1.f - 2.f / (e + 1.f);
      if (t >= 256 && l == 0) out[t - 256] = vt;
      if (l > t)            a0 = fmaf(vt, w0, a0);
      if (l + 64 > t)       a1 = fmaf(vt, w1, a1);
      if (l + 128 > t)      a2 = fmaf(vt, w2, a2);
      if (l + 192 > t)      a3 = fmaf(vt, w3, a3);
      if (l + 256 > t && l + 256 < HOUT) a4 = fmaf(vt, w4, a4);
      if (tt + 1 < nrows) PRER(tt + 1);
    }
  };

  LOADT(0); WRITET(0); PRER(0);

#define TILE_STEP(tb, B, nr)                                    \
  { if ((tb) < 8) LOADT((tb) + 1);                              \
    inner(std::integral_constant<int, B>{}, (tb), (nr));        \
    if ((tb) < 8) { WRITET((tb) + 1); PRER(0); } }

  TILE_STEP(0, 0, 32)
  TILE_STEP(1, 0, 32)
  TILE_STEP(2, 1, 32)
  TILE_STEP(3, 1, 32)
  TILE_STEP(4, 2, 32)
  TILE_STEP(5, 2, 32)
  TILE_STEP(6, 3, 32)
  TILE_STEP(7, 3, 32)
  TILE_STEP(8, 4, 4)
#undef TILE_STEP
}

// ---------------------------------------------------------------------------
extern "C" void kernel_launch(void* const* d_in, const int* in_sizes, int n_in,
                              void* d_out, int out_size, void* d_ws, size_t ws_size,
                              hipStream_t stream)
{
  const float* X   = (const float*)d_in[0];
  const float* Wq  = (const float*)d_in[1];
  const float* bq  = (const float*)d_in[2];
  const float* Wk  = (const float*)d_in[3];
  const float* bk  = (const float*)d_in[4];
  const float* Wv  = (const float*)d_in[5];
  const float* bv  = (const float*)d_in[6];
  const float* wmu = (const float*)d_in[7];
  const float* wsg = (const float*)d_in[8];
  const float* bmu = (const float*)d_in[9];
  const float* bsg = (const float*)d_in[10];
  const float* epw = (const float*)d_in[11];
  const float* epb = (const float*)d_in[12];

  char* p = (char*)d_ws;
  auto alloc = [&](size_t bytes) -> char* {
    char* r = p;
    p += (bytes + 255) & ~(size_t)255;
    return r;
  };
  char* XbT2 = alloc((size_t)64 * 65536);                            // 4MB
  unsigned short* PQK = (unsigned short*)alloc((size_t)8 * 256 * KP * 2);  // 32MB
  unsigned short* Qbf = (unsigned short*)alloc((size_t)256 * KP * 2);      // 4MB
  unsigned short* Kbf = (unsigned short*)alloc((size_t)256 * KP * 2);      // 4MB
  float* LP   = (float*)alloc((size_t)16 * 65536 * 4);               // 4MB
  float* abar = (float*)alloc(256 * 4);
  float* y    = (float*)alloc(7686 * 4);
  float* ctx  = (float*)alloc(7686 * 4);
  float* base = (float*)alloc(HOUT * 4);
  float* WsG  = (float*)alloc((size_t)HOUT * HOUT * 4 + 1024);

  prep_x2<<<dim3(256), dim3(256), 0, stream>>>(X, XbT2);
  hipMemsetAsync(abar, 0, 256 * 4, stream);
  hipMemsetAsync(base, 0, HOUT * 4, stream);

  gemm_qk5<<<dim3(241, 2, 4), dim3(512), 0, stream>>>(XbT2, Wq, Wk, PQK);
  reduce_qk4<<<dim3(64, 2), dim3(128), 0, stream>>>(PQK, bq, bk, Qbf, Kbf);
  gemm_logits<<<dim3(4, 1, 16), dim3(512), 0, stream>>>(Qbf, Kbf, LP);
  softmax_fused<<<dim3(256), dim3(256), 0, stream>>>(LP, abar);
  y_kernel<<<dim3(31), dim3(256), 0, stream>>>(X, abar, y);
  ctx_mv<<<dim3(961), dim3(512), 0, stream>>>(Wv, y, bv, ctx);
  base_kernel<<<dim3(256), dim3(320), 0, stream>>>(wmu, wsg, epw, ctx, base);
  ws_kernel<<<dim3(260), dim3(320), 0, stream>>>(wmu, wsg, epw, WsG);
  scan2<<<dim3(1), dim3(64), 0, stream>>>(WsG, base, bmu, bsg, epb, (float*)d_out);
}